// Round 18
// baseline (435.799 us; speedup 1.0000x reference)
//
#include <hip/hip_runtime.h>
#include <hip/hip_bf16.h>
#include <stdint.h>

// CriticGNN: two GraphConv branches + MLP head.
// R0: aggregate AFTER the 128->16 transform (segment_sum is linear).
// R1: runtime dtype detection (bf16 vs f32 device buffers).
// R2: CSR (counting sort by dst) + gather instead of f32 atomics.
// R3: two-level bucketed counting sort (LDS histograms, burst writes).
// R7: block-local LDS counting sort in k_bucket_bin (full-line writes).
// R8: weights to f32 in ws (s_load path); fold W2s/W2n through W_in.
// R9: k_bucket_fine LDS-staged scatter (176->30 MB writes).
// R10/R11: LDS-tiled transform1 (coalesced staging, FETCH 191->50 MB).
// R14-R19: transform1 512 threads, staged unpack, batched ds_reads (~54us).
// R18: XCD-parity gather launches. R20: 4-lane gathers + 512-thr fine.
// R21: int4 hist/bin loads. R22/R24: 435us verified best.
// R23: LDS-atomic bucket-gather 677us -> reverted (atomics are serial).
// R25 (this round): transform1's residual stall is the s_load weight
//     chain (~128 s_load_dwordx4/wave, ~12 in flight at SGPR=80 -> ~11
//     serialized K$ batches, lgkmcnt-mixed with ds_reads). Stage the
//     16KB weight matrix in LDS and read wave-uniform broadcast
//     ds_read_b128 (conflict-free, in-order FIFO, pipelines with x
//     reads). LDS 32->48KB: 3 blocks/CU = 24 waves/CU ~= measured 22.4.
//     Bit-identical arithmetic; single-kernel change.

#define F_IN 128
#define NBMAX 512   // max coarse buckets (N <= 131072)
#define BIN_CH 16
#define BIN_EDGES (256 * BIN_CH)
#define FINE_CAP 12288

// ---- wbuf (f32 weights) layout, in floats ----
#define OW1P  0        // [128][32] packed self||nbr (protein)
#define OB1P  4096     // [16]
#define OW1L  4112     // [128][32] (ligand)
#define OB1L  8208     // [16]
#define OC1P  8224     // [16][60] = wp2s @ w_in[0:50]
#define OC2P  9184     // [16][60] = wp2n @ w_in[0:50]
#define OC1L  10144    // [16][60] = wl2s @ w_in[50:100]
#define OC2L  11104    // [16][60] = wl2n @ w_in[50:100]
#define OBIN  12064    // [60] = b_in + bp2@w_in[0:50] + bl2@w_in[50:100]
#define OWHID 12124    // [70][10]
#define OBHID 12824    // [10]
#define OWOUT 12834    // [10]
#define OBOUT 12844    // [1]
#define WBUF_FLOATS 16384

__device__ __forceinline__ float bf2f(unsigned short u) {
    union { unsigned int i; float f; } v; v.i = ((unsigned int)u) << 16; return v.f;
}
__device__ __forceinline__ float bflo(unsigned int u) {
    union { unsigned int i; float f; } v; v.i = u << 16; return v.f;
}
__device__ __forceinline__ float bfhi(unsigned int u) {
    union { unsigned int i; float f; } v; v.i = u & 0xffff0000u; return v.f;
}
__device__ __forceinline__ unsigned short f2bf(float f) {
    union { float f; unsigned int i; } v; v.f = f;
    unsigned int u = v.i;
    unsigned int r = (u + 0x7fffu + ((u >> 16) & 1u)) >> 16;  // RNE
    return (unsigned short)r;
}
__device__ __forceinline__ unsigned pack2bf(float a, float b) {
    return (unsigned)f2bf(a) | ((unsigned)f2bf(b) << 16);
}
__device__ __forceinline__ float ldf(const void* p, int isf32, size_t i) {
    return isf32 ? ((const float*)p)[i] : bf2f(((const unsigned short*)p)[i]);
}

// ---------------- weight prep (+ per-block dtype probe, + cnt zeroing) ------

struct PW {
    const void *wp1s, *wp1n, *bp1, *wl1s, *wl1n, *bl1;
    const void *wp2s, *wp2n, *bp2, *wl2s, *wl2n, *bl2;
    const void *w_in, *b_in, *w_hid, *b_hid, *w_out, *b_out;
};

__global__ __launch_bounds__(256) void k_prepw(
    PW P, const unsigned short* __restrict__ px, float* __restrict__ wb,
    int* __restrict__ flag, int* __restrict__ zp, int zn)
{
    // per-block dtype probe (deterministic; every block computes the same)
    __shared__ int cnt_s;
    if (threadIdx.x == 0) cnt_s = 0;
    __syncthreads();
    int bad = 0;
    for (int i = threadIdx.x; i < 4096; i += 256) {
        unsigned e = (px[i] >> 7) & 0xFFu;
        if (e >= 140u) bad++;
    }
    atomicAdd(&cnt_s, bad);
    __syncthreads();
    const int isf32 = (cnt_s > 4096 / 16) ? 1 : 0;
    if (threadIdx.x == 0 && blockIdx.x == 0) *flag = isf32;

    int t = blockIdx.x * 256 + threadIdx.x;
    int stride = gridDim.x * 256;
    for (int i = t; i < zn; i += stride) zp[i] = 0;   // hist counters

    for (int i = t; i < 4096; i += stride) {
        int k = i >> 5, j = i & 31;
        wb[OW1P + i] = (j < 16) ? ldf(P.wp1s, isf32, k * 16 + j)
                                : ldf(P.wp1n, isf32, k * 16 + (j - 16));
        wb[OW1L + i] = (j < 16) ? ldf(P.wl1s, isf32, k * 16 + j)
                                : ldf(P.wl1n, isf32, k * 16 + (j - 16));
    }
    for (int i = t; i < 16; i += stride) {
        wb[OB1P + i] = ldf(P.bp1, isf32, i);
        wb[OB1L + i] = ldf(P.bl1, isf32, i);
    }
    for (int i = t; i < 960; i += stride) {
        int k = i / 60, j = i % 60;
        float s1 = 0.f, s2 = 0.f;
        for (int r = 0; r < 50; ++r) {
            float wi = ldf(P.w_in, isf32, r * 60 + j);
            s1 += ldf(P.wp2s, isf32, k * 50 + r) * wi;
            s2 += ldf(P.wp2n, isf32, k * 50 + r) * wi;
        }
        wb[OC1P + i] = s1; wb[OC2P + i] = s2;
    }
    for (int i = t; i < 960; i += stride) {
        int k = i / 60, j = i % 60;
        float s1 = 0.f, s2 = 0.f;
        for (int r = 0; r < 50; ++r) {
            float wi = ldf(P.w_in, isf32, (50 + r) * 60 + j);
            s1 += ldf(P.wl2s, isf32, k * 50 + r) * wi;
            s2 += ldf(P.wl2n, isf32, k * 50 + r) * wi;
        }
        wb[OC1L + i] = s1; wb[OC2L + i] = s2;
    }
    for (int i = t; i < 60; i += stride) {
        float s = ldf(P.b_in, isf32, i);
        for (int r = 0; r < 50; ++r) {
            s += ldf(P.bp2, isf32, r) * ldf(P.w_in, isf32, r * 60 + i);
            s += ldf(P.bl2, isf32, r) * ldf(P.w_in, isf32, (50 + r) * 60 + i);
        }
        wb[OBIN + i] = s;
    }
    for (int i = t; i < 700; i += stride) wb[OWHID + i] = ldf(P.w_hid, isf32, i);
    for (int i = t; i < 10; i += stride) {
        wb[OBHID + i] = ldf(P.b_hid, isf32, i);
        wb[OWOUT + i] = ldf(P.w_out, isf32, i);
    }
    if (t == 0) wb[OBOUT] = ldf(P.b_out, isf32, 0);
}

// ---------------- bucketed CSR build (both graphs via blockIdx.y) ----------------

// int4-vectorized dst reads (grid-stride over int4 + scalar tail)
__global__ __launch_bounds__(256) void k_bucket_hist(
    const int* __restrict__ ed0, const int* __restrict__ ed1,
    int* __restrict__ cnt, int nE)
{
    const int* ed = blockIdx.y ? ed1 : ed0;
    int* c = cnt + blockIdx.y * NBMAX;
    __shared__ int h[NBMAX];
    for (int i = threadIdx.x; i < NBMAX; i += 256) h[i] = 0;
    __syncthreads();
    int gid = blockIdx.x * 256 + threadIdx.x;
    int stride = gridDim.x * 256;
    int nE4 = nE >> 2;
    const int4* ed4 = (const int4*)ed;
    for (int i = gid; i < nE4; i += stride) {
        int4 v = ed4[i];
        atomicAdd(&h[v.x >> 8], 1);
        atomicAdd(&h[v.y >> 8], 1);
        atomicAdd(&h[v.z >> 8], 1);
        atomicAdd(&h[v.w >> 8], 1);
    }
    for (int e = (nE4 << 2) + gid; e < nE; e += stride)
        atomicAdd(&h[ed[e] >> 8], 1);
    __syncthreads();
    for (int i = threadIdx.x; i < NBMAX; i += 256)
        if (h[i]) atomicAdd(&c[i], h[i]);
}

__global__ __launch_bounds__(512) void k_bucket_scan(
    const int* __restrict__ cnt, int* __restrict__ base,
    int* __restrict__ cursor, int nb)
{
    const int* c = cnt + blockIdx.x * NBMAX;
    int* ba = base + blockIdx.x * 528;
    int* cu = cursor + blockIdx.x * NBMAX;
    __shared__ int sh[512];
    int t = threadIdx.x;
    int v = (t < nb) ? c[t] : 0;
    sh[t] = v;
    __syncthreads();
    for (int off = 1; off < 512; off <<= 1) {
        int x = (t >= off) ? sh[t - off] : 0;
        __syncthreads();
        sh[t] += x;
        __syncthreads();
    }
    int excl = sh[t] - v;
    if (t < nb) { ba[t] = excl; cu[t] = excl; }
    if (t == nb - 1) ba[nb] = excl + v;
}

// each thread owns a contiguous 16-edge range -> 4x int4 loads per array.
__global__ __launch_bounds__(256) void k_bucket_bin(
    const int* __restrict__ es0, const int* __restrict__ ed0,
    const int* __restrict__ es1, const int* __restrict__ ed1,
    int* __restrict__ cursor, unsigned* __restrict__ pairs, int nE)
{
    const int* es = blockIdx.y ? es1 : es0;
    const int* ed = blockIdx.y ? ed1 : ed0;
    int* cur = cursor + blockIdx.y * NBMAX;
    unsigned* pr = pairs + (size_t)blockIdx.y * nE;

    __shared__ int h[NBMAX];              // hist, then delta (= gbase - lbase)
    __shared__ int lcur[NBMAX];           // block-local base, then LDS cursor
    __shared__ int sh[256];               // scan scratch
    __shared__ unsigned stage[BIN_EDGES]; // payload grouped by bucket
    __shared__ unsigned short stageB[BIN_EDGES]; // bucket id per slot

    for (int i = threadIdx.x; i < NBMAX; i += 256) h[i] = 0;
    __syncthreads();
    int e0 = blockIdx.x * BIN_EDGES;
    int eb = e0 + threadIdx.x * BIN_CH;   // this thread's contiguous range
    int s[BIN_CH], d[BIN_CH];
    if (eb + BIN_CH <= nE) {
#pragma unroll
        for (int k4 = 0; k4 < BIN_CH / 4; ++k4) {
            int4 sv = *(const int4*)(es + eb + k4 * 4);
            int4 dv = *(const int4*)(ed + eb + k4 * 4);
            s[k4 * 4 + 0] = sv.x; d[k4 * 4 + 0] = dv.x;
            s[k4 * 4 + 1] = sv.y; d[k4 * 4 + 1] = dv.y;
            s[k4 * 4 + 2] = sv.z; d[k4 * 4 + 2] = dv.z;
            s[k4 * 4 + 3] = sv.w; d[k4 * 4 + 3] = dv.w;
        }
#pragma unroll
        for (int k = 0; k < BIN_CH; ++k)
            atomicAdd(&h[d[k] >> 8], 1);
    } else {
#pragma unroll
        for (int k = 0; k < BIN_CH; ++k) {
            int e = eb + k;
            if (e < nE) {
                s[k] = es[e]; d[k] = ed[e];
                atomicAdd(&h[d[k] >> 8], 1);
            } else d[k] = -1;
        }
    }
    __syncthreads();
    {
        int t = threadIdx.x;
        int a = h[2 * t], b2 = h[2 * t + 1];
        sh[t] = a + b2;
        __syncthreads();
        for (int off = 1; off < 256; off <<= 1) {
            int x = (t >= off) ? sh[t - off] : 0;
            __syncthreads();
            sh[t] += x;
            __syncthreads();
        }
        int excl = sh[t] - (a + b2);
        lcur[2 * t] = excl;
        lcur[2 * t + 1] = excl + a;
    }
    __syncthreads();
    for (int b = threadIdx.x; b < NBMAX; b += 256) {
        int c = h[b];
        if (c) {
            int g = atomicAdd(&cur[b], c);
            h[b] = g - lcur[b];
        }
    }
    __syncthreads();
    if (eb + BIN_CH <= nE) {
#pragma unroll
        for (int k = 0; k < BIN_CH; ++k) {
            int b = d[k] >> 8;
            int pos = atomicAdd(&lcur[b], 1);
            stage[pos] = ((unsigned)(d[k] & 255) << 24) | (unsigned)s[k];
            stageB[pos] = (unsigned short)b;
        }
    } else {
#pragma unroll
        for (int k = 0; k < BIN_CH; ++k) {
            if (d[k] >= 0) {
                int b = d[k] >> 8;
                int pos = atomicAdd(&lcur[b], 1);
                stage[pos] = ((unsigned)(d[k] & 255) << 24) | (unsigned)s[k];
                stageB[pos] = (unsigned short)b;
            }
        }
    }
    __syncthreads();
    int total = nE - e0; if (total > BIN_EDGES) total = BIN_EDGES;
    for (int i = threadIdx.x; i < total; i += 256)
        pr[h[stageB[i]] + i] = stage[i];
}

// within-bucket fine sort; srcs writes staged in LDS -> full-line stores.
// 512 threads (2x waves/CU); 256-entry scan on first 256 lanes.
__global__ __launch_bounds__(512) void k_bucket_fine(
    const unsigned* __restrict__ pairs, const int* __restrict__ base,
    int* __restrict__ row0, int* __restrict__ srcs0,
    int* __restrict__ row1, int* __restrict__ srcs1,
    int n, int nE, int nb)
{
    const unsigned* pr = pairs + (size_t)blockIdx.y * nE;
    const int* ba = base + blockIdx.y * 528;
    int* row = blockIdx.y ? row1 : row0;
    int* srcs = blockIdx.y ? srcs1 : srcs0;
    __shared__ int cnt[256], cur[256];
    __shared__ int stage[FINE_CAP];
    int b = blockIdx.x;
    int t = threadIdx.x;
    int s0 = ba[b], s1 = ba[b + 1];
    int m = s1 - s0;
    if (t < 256) cnt[t] = 0;
    __syncthreads();
    for (int i = s0 + t; i < s1; i += 512)
        atomicAdd(&cnt[pr[i] >> 24], 1);
    __syncthreads();
    int c = (t < 256) ? cnt[t] : 0;
    if (t < 256) cur[t] = c;
    __syncthreads();
    for (int off = 1; off < 256; off <<= 1) {
        int x = (t < 256 && t >= off) ? cur[t - off] : 0;
        __syncthreads();
        if (t < 256) cur[t] += x;
        __syncthreads();
    }
    int excl = (t < 256) ? (cur[t] - c) : 0;
    __syncthreads();
    int node = (b << 8) + t;
    if (t < 256 && node < n) row[node] = s0 + excl;
    if (b == nb - 1 && t == 0) row[n] = nE;
    if (m <= FINE_CAP) {
        if (t < 256) cur[t] = excl;          // bucket-local cursor
        __syncthreads();
        for (int i = s0 + t; i < s1; i += 512) {
            unsigned p = pr[i];
            int slot = atomicAdd(&cur[p >> 24], 1);
            stage[slot] = (int)(p & 0xFFFFFFu);
        }
        __syncthreads();
        for (int i = t; i < m; i += 512)     // coalesced copy-out
            srcs[s0 + i] = stage[i];
    } else {                                 // fallback: direct scatter
        if (t < 256) cur[t] = s0 + excl;
        __syncthreads();
        for (int i = s0 + t; i < s1; i += 512) {
            unsigned p = pr[i];
            int slot = atomicAdd(&cur[p >> 24], 1);
            srcs[slot] = (int)(p & 0xFFFFFFu);
        }
    }
}

// ---------------- dense compute ----------------

struct TArgs2 {
    const void* __restrict__ x;
    const float* __restrict__ w;     // [128][32] packed self||nbr
    const float* __restrict__ b;     // [16]
    float* __restrict__ acc;
    void* __restrict__ nbr;
};

// 64-node / 32KB f32 x-tile + 16KB LDS weights; bf16 converted once at
// staging. 512 threads = 8 waves, 4 cols/wave (jq wave-uniform).
// R25: weights read as wave-uniform broadcast ds_read_b128 from LDS
// (replaces the serialized s_load K$ chain). 48KB LDS -> 3 blocks/CU.
__global__ __launch_bounds__(512) void k_transform1(
    TArgs2 a0, TArgs2 a1, int n, const int* __restrict__ flag)
{
    TArgs2 A = blockIdx.y ? a1 : a0;
    const int isf32 = *flag;
    __shared__ float xs[64 * 128];              // 32 KB
    __shared__ float wl[128 * 32];              // 16 KB weights
    const int t = threadIdx.x;
    const int tile0 = blockIdx.x * 64;

    // stage weights (coalesced f32, 8 per thread)
#pragma unroll
    for (int i = 0; i < 8; ++i)
        wl[i * 512 + t] = A.w[i * 512 + t];

    if (isf32) {
        const float4* xg = (const float4*)A.x;  // 16B units
        float4* xl = (float4*)xs;
#pragma unroll
        for (int i = 0; i < 4; ++i) {           // 64 rows x 32 chunks
            int flat = i * 512 + t;
            int row = flat >> 5, ck = flat & 31;
            if (tile0 + row < n)
                xl[row * 32 + (ck ^ (row & 7))] =
                    xg[((size_t)(tile0 + row)) * 32 + ck];
        }
    } else {
        const uint4* xg = (const uint4*)A.x;
        float4* xl = (float4*)xs;
#pragma unroll
        for (int i = 0; i < 2; ++i) {           // 64 rows x 16 bf16-chunks
            int flat = i * 512 + t;
            int row = flat >> 4, ck = flat & 15;
            if (tile0 + row < n) {
                uint4 q = xg[((size_t)(tile0 + row)) * 16 + ck];
                float4 lo = make_float4(bflo(q.x), bfhi(q.x), bflo(q.y), bfhi(q.y));
                float4 hi = make_float4(bflo(q.z), bfhi(q.z), bflo(q.w), bfhi(q.w));
                xl[row * 32 + ((2 * ck) ^ (row & 7))] = lo;
                xl[row * 32 + ((2 * ck + 1) ^ (row & 7))] = hi;
            }
        }
    }
    __syncthreads();

    const int jq = __builtin_amdgcn_readfirstlane(t >> 6); // col octile 0..7
    const int r = t & 63;                                  // tile-local row
    const int node = tile0 + r;
    if (node >= n) return;
    const int sw = r & 7;

    float acc[4];
    if (jq < 4) {
#pragma unroll
        for (int j = 0; j < 4; ++j) acc[j] = A.b[4 * jq + j];
    } else {
#pragma unroll
        for (int j = 0; j < 4; ++j) acc[j] = 0.f;
    }

    const float4* xl = (const float4*)xs + r * 32;
    const float* __restrict__ wbase = wl + 4 * jq;   // wave-uniform base
    for (int kb = 0; kb < 4; ++kb) {            // 4 batches of 8 chunks
        float4 xq[8];
#pragma unroll
        for (int u = 0; u < 8; ++u)             // 8 ds_reads issued together
            xq[u] = xl[(kb * 8 + u) ^ sw];
#pragma unroll
        for (int u = 0; u < 8; ++u) {
            int kk = kb * 8 + u;
            float xv[4] = {xq[u].x, xq[u].y, xq[u].z, xq[u].w};
#pragma unroll
            for (int h = 0; h < 4; ++h) {
                // broadcast ds_read_b128: same addr across the wave
                float4 wv = *(const float4*)(wbase + (kk * 4 + h) * 32);
                acc[0] += xv[h] * wv.x;
                acc[1] += xv[h] * wv.y;
                acc[2] += xv[h] * wv.z;
                acc[3] += xv[h] * wv.w;
            }
        }
    }

    if (jq < 4) {
        float4* a4 = (float4*)(A.acc + (size_t)node * 16);
        a4[jq] = make_float4(acc[0], acc[1], acc[2], acc[3]);
    } else {
        unsigned short* nrow = (unsigned short*)A.nbr + ((size_t)node << 4)
                               + ((jq - 4) << 2);
        *(uint2*)nrow = make_uint2(pack2bf(acc[0], acc[1]),
                                   pack2bf(acc[2], acc[3]));
    }
}

struct GArgs { const int *row, *srcs; const void* val; float* out; void* rout; };

// out[node,0:16] (f32) = (selfmode ? out[node] : 0) + sum_{nbrs} bf16row val[s]
// selfmode additionally writes rout[node] = bf16(relu(out-row)).
// 1D grid; graph = blockIdx&1 (XCD parity: one 3.2MB val table per XCD L2).
// 4 lanes/node = 2 col-halves x 2 edge-halves; shfl_xor(2) combine.
__global__ __launch_bounds__(256) void k_gather16(
    GArgs g0, GArgs g1, int n, int selfmode)
{
    GArgs G = (blockIdx.x & 1) ? g1 : g0;
    int t = (blockIdx.x >> 1) * 256 + threadIdx.x;
    int node = t >> 2;
    if (node >= n) return;
    const int q = t & 3;
    const int e2 = q >> 1;          // edge half
    const int c = (q & 1) << 3;     // bf16 col offset: 0 or 8
    const unsigned short* vb = (const unsigned short*)G.val;
    int rs = G.row[node], re = G.row[node + 1];
    int half = (re - rs + 1) >> 1;
    int jb = e2 ? (rs + half) : rs;
    int je = e2 ? re : (rs + half);
    float4 sa = make_float4(0.f, 0.f, 0.f, 0.f);
    float4 sb = make_float4(0.f, 0.f, 0.f, 0.f);
    int j = jb;
    for (; j + 16 <= je; j += 16) {
        int s[16];
        uint4 v[16];
#pragma unroll
        for (int u = 0; u < 16; ++u) s[u] = G.srcs[j + u];
#pragma unroll
        for (int u = 0; u < 16; ++u)
            v[u] = *(const uint4*)(vb + (((size_t)s[u]) << 4) + c);
#pragma unroll
        for (int u = 0; u < 16; ++u) {
            sa.x += bflo(v[u].x); sa.y += bfhi(v[u].x);
            sa.z += bflo(v[u].y); sa.w += bfhi(v[u].y);
            sb.x += bflo(v[u].z); sb.y += bfhi(v[u].z);
            sb.z += bflo(v[u].w); sb.w += bfhi(v[u].w);
        }
    }
    for (; j + 8 <= je; j += 8) {
        int s[8];
        uint4 v[8];
#pragma unroll
        for (int u = 0; u < 8; ++u) s[u] = G.srcs[j + u];
#pragma unroll
        for (int u = 0; u < 8; ++u)
            v[u] = *(const uint4*)(vb + (((size_t)s[u]) << 4) + c);
#pragma unroll
        for (int u = 0; u < 8; ++u) {
            sa.x += bflo(v[u].x); sa.y += bfhi(v[u].x);
            sa.z += bflo(v[u].y); sa.w += bfhi(v[u].y);
            sb.x += bflo(v[u].z); sb.y += bfhi(v[u].z);
            sb.z += bflo(v[u].w); sb.w += bfhi(v[u].w);
        }
    }
    for (; j < je; ++j) {
        uint4 v = *(const uint4*)(vb + (((size_t)G.srcs[j]) << 4) + c);
        sa.x += bflo(v.x); sa.y += bfhi(v.x);
        sa.z += bflo(v.y); sa.w += bfhi(v.y);
        sb.x += bflo(v.z); sb.y += bfhi(v.z);
        sb.z += bflo(v.w); sb.w += bfhi(v.w);
    }
    // combine edge halves (lanes differ in bit 1)
    sa.x += __shfl_xor(sa.x, 2); sa.y += __shfl_xor(sa.y, 2);
    sa.z += __shfl_xor(sa.z, 2); sa.w += __shfl_xor(sa.w, 2);
    sb.x += __shfl_xor(sb.x, 2); sb.y += __shfl_xor(sb.y, 2);
    sb.z += __shfl_xor(sb.z, 2); sb.w += __shfl_xor(sb.w, 2);
    if (e2 == 0) {
        float4* o4 = (float4*)(G.out + ((size_t)node << 4) + c);
        if (selfmode) {
            float4 pa = o4[0], pb = o4[1];
            sa.x += pa.x; sa.y += pa.y; sa.z += pa.z; sa.w += pa.w;
            sb.x += pb.x; sb.y += pb.y; sb.z += pb.z; sb.w += pb.w;
        }
        o4[0] = sa; o4[1] = sb;
        if (selfmode) {
            unsigned short* orow = (unsigned short*)G.rout + ((size_t)node << 4) + c;
            *(uint4*)orow = make_uint4(
                pack2bf(fmaxf(sa.x, 0.f), fmaxf(sa.y, 0.f)),
                pack2bf(fmaxf(sa.z, 0.f), fmaxf(sa.w, 0.f)),
                pack2bf(fmaxf(sb.x, 0.f), fmaxf(sb.y, 0.f)),
                pack2bf(fmaxf(sb.z, 0.f), fmaxf(sb.w, 0.f)));
        }
    }
}

// fp[30] accumulate: fp += f(row) @ C[:, jo:jo+30]  where C is [16][60] at wb+off
__device__ __forceinline__ void fp_acc30(float* fp, const float* __restrict__ wb,
                                         int off, int jo,
                                         const float* __restrict__ row, bool dorelu)
{
    const float4* r4 = (const float4*)row;
    for (int kk = 0; kk < 4; ++kk) {
        float4 v = r4[kk];
        float xs[4] = {v.x, v.y, v.z, v.w};
        if (dorelu) {
            xs[0] = fmaxf(xs[0], 0.f); xs[1] = fmaxf(xs[1], 0.f);
            xs[2] = fmaxf(xs[2], 0.f); xs[3] = fmaxf(xs[3], 0.f);
        }
        const float* __restrict__ wq = wb + off + kk * 240 + jo;
#pragma unroll
        for (int h = 0; h < 4; ++h) {
#pragma unroll
            for (int j = 0; j < 30; ++j) fp[j] += xs[h] * wq[h * 60 + j];
        }
    }
}

// fused layer2(nbr part via folded weights) + MLP head; 128 nodes/block,
// wave pairs split fp[60] -> fp[30] each; h[10] partials combined via LDS.
__global__ __launch_bounds__(256) void k_headf(
    const float* __restrict__ hP, const float* __restrict__ gP,
    const float* __restrict__ hL, const float* __restrict__ gL,
    const void* __restrict__ action, const float* __restrict__ wb,
    void* __restrict__ out, int n, const int* __restrict__ flag)
{
    const int isf32 = *flag;
    __shared__ float hbuf[128][10];
    int w = threadIdx.x >> 6;
    int jh = __builtin_amdgcn_readfirstlane(w & 1);
    int slot = ((w >> 1) << 6) + (threadIdx.x & 63);
    int node = blockIdx.x * 128 + slot;
    int nodec = node < n ? node : (n - 1);
    const int jo = 30 * jh;

    float fp[30];
#pragma unroll
    for (int j = 0; j < 30; ++j) fp[j] = wb[OBIN + jo + j];

    fp_acc30(fp, wb, OC1P, jo, hP + (size_t)nodec * 16, true);
    fp_acc30(fp, wb, OC2P, jo, gP + (size_t)nodec * 16, false);
    fp_acc30(fp, wb, OC1L, jo, hL + (size_t)nodec * 16, true);
    fp_acc30(fp, wb, OC2L, jo, gL + (size_t)nodec * 16, false);

    float h[10];
#pragma unroll
    for (int j = 0; j < 10; ++j) h[j] = (jh == 0) ? wb[OBHID + j] : 0.f;
#pragma unroll
    for (int k = 0; k < 30; ++k) {
        float v = fmaxf(fp[k], 0.f);
#pragma unroll
        for (int j = 0; j < 10; ++j) h[j] += v * wb[OWHID + (jo + k) * 10 + j];
    }
    if (jh) {
#pragma unroll
        for (int j = 0; j < 10; ++j) hbuf[slot][j] = h[j];
    }
    __syncthreads();
    if (jh == 0) {
#pragma unroll
        for (int j = 0; j < 10; ++j) h[j] += hbuf[slot][j];
#pragma unroll
        for (int k = 0; k < 10; ++k) {
            float v = ldf(action, isf32, (size_t)nodec * 10 + k);
#pragma unroll
            for (int j = 0; j < 10; ++j) h[j] += v * wb[OWHID + (60 + k) * 10 + j];
        }
        float o = wb[OBOUT];
#pragma unroll
        for (int j = 0; j < 10; ++j) o += fmaxf(h[j], 0.f) * wb[OWOUT + j];
        if (node < n) {
            if (isf32) ((float*)out)[node] = o;
            else       ((unsigned short*)out)[node] = f2bf(o);
        }
    }
}

extern "C" void kernel_launch(void* const* d_in, const int* in_sizes, int n_in,
                              void* d_out, int out_size, void* d_ws, size_t ws_size,
                              hipStream_t stream)
{
    const void* px   = d_in[0];
    const int*  pe   = (const int*)d_in[1];
    const void* lx   = d_in[2];
    const int*  le   = (const int*)d_in[3];
    const void* act  = d_in[4];

    const int N = in_sizes[0] / F_IN;
    const int E = in_sizes[1] / 2;
    const int NB = (N + 255) >> 8;

    // header: flag(64) | cnt(2*512) | base(2*528) | cursor(2*512) = 3200 ints
    int* flag    = (int*)d_ws;
    int* cnt     = flag + 64;
    int* base    = cnt + 2 * NBMAX;
    int* cursorB = base + 2 * 528;
    float* wbuf  = (float*)(flag + 3200);
    int* rowP    = flag + 3200 + WBUF_FLOATS;
    int* srcsP   = rowP + (N + 64);
    int* rowL    = srcsP + E;
    int* srcsL   = rowL + (N + 64);
    float* dense = (float*)(srcsL + E);
    unsigned* pairs = (unsigned*)dense;   // 2E uints; dead before dense writes

    float* accP = dense;                       // [N][16] f32 (h1_P, stays live)
    float* accL = accP + (size_t)N * 16;       // [N][16] f32
    float* aggP = accL + (size_t)N * 16;       // [N][16] f32 (gather-2 out)
    float* aggL = aggP + (size_t)N * 16;       // [N][16] f32
    void*  n1P  = (void*)(aggL + (size_t)N * 16);       // [N][16] bf16
    void*  n1L  = (void*)((float*)n1P + (size_t)N * 8); // [N][16] bf16
    void*  n2P  = (void*)((float*)n1L + (size_t)N * 8); // [N][16] bf16 relu(h1)
    void*  n2L  = (void*)((float*)n2P + (size_t)N * 8); // [N][16] bf16

    const int nb64 = (N + 63) / 64;
    const int nb128 = (N + 127) / 128;
    const int gb4 = (N * 4 + 255) / 256;
    const int bb = (E + BIN_EDGES - 1) / BIN_EDGES;

    // prepw: weights + per-block dtype probe + cnt zeroing
    PW P{d_in[5], d_in[6], d_in[7], d_in[11], d_in[12], d_in[13],
         d_in[8], d_in[9], d_in[10], d_in[14], d_in[15], d_in[16],
         d_in[17], d_in[18], d_in[19], d_in[20], d_in[21], d_in[22]};
    k_prepw<<<64, 256, 0, stream>>>(P, (const unsigned short*)px, wbuf,
                                    flag, cnt, 2 * NBMAX);

    // ---- CSR build for both graphs (blockIdx.y = graph) ----
    k_bucket_hist<<<dim3(256, 2), 256, 0, stream>>>(pe + E, le + E, cnt, E);
    k_bucket_scan<<<2, 512, 0, stream>>>(cnt, base, cursorB, NB);
    k_bucket_bin<<<dim3(bb, 2), 256, 0, stream>>>(pe, pe + E, le, le + E,
                                                  cursorB, pairs, E);
    k_bucket_fine<<<dim3(NB, 2), 512, 0, stream>>>(pairs, base, rowP, srcsP,
                                                   rowL, srcsL, N, E, NB);

    // ---- dense pipeline ----
    TArgs2 tP{px, wbuf + OW1P, wbuf + OB1P, accP, n1P};
    TArgs2 tL{lx, wbuf + OW1L, wbuf + OB1L, accL, n1L};
    k_transform1<<<dim3(nb64, 2), 512, 0, stream>>>(tP, tL, N, flag);

    // gather-1 (self+agg), fused relu->bf16 into n2; 1D grid, graph=bid&1
    GArgs g1P{rowP, srcsP, n1P, accP, n2P}, g1L{rowL, srcsL, n1L, accL, n2L};
    k_gather16<<<gb4 * 2, 256, 0, stream>>>(g1P, g1L, N, 1);

    // gather-2 (agg of relu'd h1)
    GArgs g2P{rowP, srcsP, n2P, aggP, nullptr}, g2L{rowL, srcsL, n2L, aggL, nullptr};
    k_gather16<<<gb4 * 2, 256, 0, stream>>>(g2P, g2L, N, 0);

    k_headf<<<nb128, 256, 0, stream>>>(accP, aggP, accL, aggL, act, wbuf,
                                       d_out, N, flag);
}

// Round 19
// 432.777 us; speedup vs baseline: 1.0070x; 1.0070x over previous
//
#include <hip/hip_runtime.h>
#include <hip/hip_bf16.h>
#include <stdint.h>

// CriticGNN: two GraphConv branches + MLP head.
// R0: aggregate AFTER the 128->16 transform (segment_sum is linear).
// R1: runtime dtype detection (bf16 vs f32 device buffers).
// R2: CSR (counting sort by dst) + gather instead of f32 atomics.
// R3: two-level bucketed counting sort (LDS histograms, burst writes).
// R7: block-local LDS counting sort in k_bucket_bin (full-line writes).
// R8: weights to f32 in ws (s_load path); fold W2s/W2n through W_in.
// R9: k_bucket_fine LDS-staged scatter (176->30 MB writes).
// R10/R11: LDS-tiled transform1 (coalesced staging, FETCH 191->50 MB).
// R14-R19: transform1 512 threads, staged unpack, batched ds_reads (~54us).
// R18: XCD-parity gather launches. R20: 4-lane gathers + 512-thr fine.
// R21: int4 hist/bin loads. R22/R24: 435us verified best.
// R23: LDS-atomic bucket-gather 677us -> reverted (atomics are serial).
// R25: LDS-broadcast weights: 58us, occ 50% -> falsified the s_load-chain
//      theory (VALUBusy pinned ~25% in both configs). transform1's ~54us
//      is invariant under every access-path substitution tried (6 variants);
//      it is structurally converged at 12% of total.
// R26 (this round): revert transform1 to the R22 s_load version ->
//      re-bank the 434.6us verified best.

#define F_IN 128
#define NBMAX 512   // max coarse buckets (N <= 131072)
#define BIN_CH 16
#define BIN_EDGES (256 * BIN_CH)
#define FINE_CAP 12288

// ---- wbuf (f32 weights) layout, in floats ----
#define OW1P  0        // [128][32] packed self||nbr (protein)
#define OB1P  4096     // [16]
#define OW1L  4112     // [128][32] (ligand)
#define OB1L  8208     // [16]
#define OC1P  8224     // [16][60] = wp2s @ w_in[0:50]
#define OC2P  9184     // [16][60] = wp2n @ w_in[0:50]
#define OC1L  10144    // [16][60] = wl2s @ w_in[50:100]
#define OC2L  11104    // [16][60] = wl2n @ w_in[50:100]
#define OBIN  12064    // [60] = b_in + bp2@w_in[0:50] + bl2@w_in[50:100]
#define OWHID 12124    // [70][10]
#define OBHID 12824    // [10]
#define OWOUT 12834    // [10]
#define OBOUT 12844    // [1]
#define WBUF_FLOATS 16384

__device__ __forceinline__ float bf2f(unsigned short u) {
    union { unsigned int i; float f; } v; v.i = ((unsigned int)u) << 16; return v.f;
}
__device__ __forceinline__ float bflo(unsigned int u) {
    union { unsigned int i; float f; } v; v.i = u << 16; return v.f;
}
__device__ __forceinline__ float bfhi(unsigned int u) {
    union { unsigned int i; float f; } v; v.i = u & 0xffff0000u; return v.f;
}
__device__ __forceinline__ unsigned short f2bf(float f) {
    union { float f; unsigned int i; } v; v.f = f;
    unsigned int u = v.i;
    unsigned int r = (u + 0x7fffu + ((u >> 16) & 1u)) >> 16;  // RNE
    return (unsigned short)r;
}
__device__ __forceinline__ unsigned pack2bf(float a, float b) {
    return (unsigned)f2bf(a) | ((unsigned)f2bf(b) << 16);
}
__device__ __forceinline__ float ldf(const void* p, int isf32, size_t i) {
    return isf32 ? ((const float*)p)[i] : bf2f(((const unsigned short*)p)[i]);
}

// ---------------- weight prep (+ per-block dtype probe, + cnt zeroing) ------

struct PW {
    const void *wp1s, *wp1n, *bp1, *wl1s, *wl1n, *bl1;
    const void *wp2s, *wp2n, *bp2, *wl2s, *wl2n, *bl2;
    const void *w_in, *b_in, *w_hid, *b_hid, *w_out, *b_out;
};

__global__ __launch_bounds__(256) void k_prepw(
    PW P, const unsigned short* __restrict__ px, float* __restrict__ wb,
    int* __restrict__ flag, int* __restrict__ zp, int zn)
{
    // per-block dtype probe (deterministic; every block computes the same)
    __shared__ int cnt_s;
    if (threadIdx.x == 0) cnt_s = 0;
    __syncthreads();
    int bad = 0;
    for (int i = threadIdx.x; i < 4096; i += 256) {
        unsigned e = (px[i] >> 7) & 0xFFu;
        if (e >= 140u) bad++;
    }
    atomicAdd(&cnt_s, bad);
    __syncthreads();
    const int isf32 = (cnt_s > 4096 / 16) ? 1 : 0;
    if (threadIdx.x == 0 && blockIdx.x == 0) *flag = isf32;

    int t = blockIdx.x * 256 + threadIdx.x;
    int stride = gridDim.x * 256;
    for (int i = t; i < zn; i += stride) zp[i] = 0;   // hist counters

    for (int i = t; i < 4096; i += stride) {
        int k = i >> 5, j = i & 31;
        wb[OW1P + i] = (j < 16) ? ldf(P.wp1s, isf32, k * 16 + j)
                                : ldf(P.wp1n, isf32, k * 16 + (j - 16));
        wb[OW1L + i] = (j < 16) ? ldf(P.wl1s, isf32, k * 16 + j)
                                : ldf(P.wl1n, isf32, k * 16 + (j - 16));
    }
    for (int i = t; i < 16; i += stride) {
        wb[OB1P + i] = ldf(P.bp1, isf32, i);
        wb[OB1L + i] = ldf(P.bl1, isf32, i);
    }
    for (int i = t; i < 960; i += stride) {
        int k = i / 60, j = i % 60;
        float s1 = 0.f, s2 = 0.f;
        for (int r = 0; r < 50; ++r) {
            float wi = ldf(P.w_in, isf32, r * 60 + j);
            s1 += ldf(P.wp2s, isf32, k * 50 + r) * wi;
            s2 += ldf(P.wp2n, isf32, k * 50 + r) * wi;
        }
        wb[OC1P + i] = s1; wb[OC2P + i] = s2;
    }
    for (int i = t; i < 960; i += stride) {
        int k = i / 60, j = i % 60;
        float s1 = 0.f, s2 = 0.f;
        for (int r = 0; r < 50; ++r) {
            float wi = ldf(P.w_in, isf32, (50 + r) * 60 + j);
            s1 += ldf(P.wl2s, isf32, k * 50 + r) * wi;
            s2 += ldf(P.wl2n, isf32, k * 50 + r) * wi;
        }
        wb[OC1L + i] = s1; wb[OC2L + i] = s2;
    }
    for (int i = t; i < 60; i += stride) {
        float s = ldf(P.b_in, isf32, i);
        for (int r = 0; r < 50; ++r) {
            s += ldf(P.bp2, isf32, r) * ldf(P.w_in, isf32, r * 60 + i);
            s += ldf(P.bl2, isf32, r) * ldf(P.w_in, isf32, (50 + r) * 60 + i);
        }
        wb[OBIN + i] = s;
    }
    for (int i = t; i < 700; i += stride) wb[OWHID + i] = ldf(P.w_hid, isf32, i);
    for (int i = t; i < 10; i += stride) {
        wb[OBHID + i] = ldf(P.b_hid, isf32, i);
        wb[OWOUT + i] = ldf(P.w_out, isf32, i);
    }
    if (t == 0) wb[OBOUT] = ldf(P.b_out, isf32, 0);
}

// ---------------- bucketed CSR build (both graphs via blockIdx.y) ----------------

// int4-vectorized dst reads (grid-stride over int4 + scalar tail)
__global__ __launch_bounds__(256) void k_bucket_hist(
    const int* __restrict__ ed0, const int* __restrict__ ed1,
    int* __restrict__ cnt, int nE)
{
    const int* ed = blockIdx.y ? ed1 : ed0;
    int* c = cnt + blockIdx.y * NBMAX;
    __shared__ int h[NBMAX];
    for (int i = threadIdx.x; i < NBMAX; i += 256) h[i] = 0;
    __syncthreads();
    int gid = blockIdx.x * 256 + threadIdx.x;
    int stride = gridDim.x * 256;
    int nE4 = nE >> 2;
    const int4* ed4 = (const int4*)ed;
    for (int i = gid; i < nE4; i += stride) {
        int4 v = ed4[i];
        atomicAdd(&h[v.x >> 8], 1);
        atomicAdd(&h[v.y >> 8], 1);
        atomicAdd(&h[v.z >> 8], 1);
        atomicAdd(&h[v.w >> 8], 1);
    }
    for (int e = (nE4 << 2) + gid; e < nE; e += stride)
        atomicAdd(&h[ed[e] >> 8], 1);
    __syncthreads();
    for (int i = threadIdx.x; i < NBMAX; i += 256)
        if (h[i]) atomicAdd(&c[i], h[i]);
}

__global__ __launch_bounds__(512) void k_bucket_scan(
    const int* __restrict__ cnt, int* __restrict__ base,
    int* __restrict__ cursor, int nb)
{
    const int* c = cnt + blockIdx.x * NBMAX;
    int* ba = base + blockIdx.x * 528;
    int* cu = cursor + blockIdx.x * NBMAX;
    __shared__ int sh[512];
    int t = threadIdx.x;
    int v = (t < nb) ? c[t] : 0;
    sh[t] = v;
    __syncthreads();
    for (int off = 1; off < 512; off <<= 1) {
        int x = (t >= off) ? sh[t - off] : 0;
        __syncthreads();
        sh[t] += x;
        __syncthreads();
    }
    int excl = sh[t] - v;
    if (t < nb) { ba[t] = excl; cu[t] = excl; }
    if (t == nb - 1) ba[nb] = excl + v;
}

// each thread owns a contiguous 16-edge range -> 4x int4 loads per array.
__global__ __launch_bounds__(256) void k_bucket_bin(
    const int* __restrict__ es0, const int* __restrict__ ed0,
    const int* __restrict__ es1, const int* __restrict__ ed1,
    int* __restrict__ cursor, unsigned* __restrict__ pairs, int nE)
{
    const int* es = blockIdx.y ? es1 : es0;
    const int* ed = blockIdx.y ? ed1 : ed0;
    int* cur = cursor + blockIdx.y * NBMAX;
    unsigned* pr = pairs + (size_t)blockIdx.y * nE;

    __shared__ int h[NBMAX];              // hist, then delta (= gbase - lbase)
    __shared__ int lcur[NBMAX];           // block-local base, then LDS cursor
    __shared__ int sh[256];               // scan scratch
    __shared__ unsigned stage[BIN_EDGES]; // payload grouped by bucket
    __shared__ unsigned short stageB[BIN_EDGES]; // bucket id per slot

    for (int i = threadIdx.x; i < NBMAX; i += 256) h[i] = 0;
    __syncthreads();
    int e0 = blockIdx.x * BIN_EDGES;
    int eb = e0 + threadIdx.x * BIN_CH;   // this thread's contiguous range
    int s[BIN_CH], d[BIN_CH];
    if (eb + BIN_CH <= nE) {
#pragma unroll
        for (int k4 = 0; k4 < BIN_CH / 4; ++k4) {
            int4 sv = *(const int4*)(es + eb + k4 * 4);
            int4 dv = *(const int4*)(ed + eb + k4 * 4);
            s[k4 * 4 + 0] = sv.x; d[k4 * 4 + 0] = dv.x;
            s[k4 * 4 + 1] = sv.y; d[k4 * 4 + 1] = dv.y;
            s[k4 * 4 + 2] = sv.z; d[k4 * 4 + 2] = dv.z;
            s[k4 * 4 + 3] = sv.w; d[k4 * 4 + 3] = dv.w;
        }
#pragma unroll
        for (int k = 0; k < BIN_CH; ++k)
            atomicAdd(&h[d[k] >> 8], 1);
    } else {
#pragma unroll
        for (int k = 0; k < BIN_CH; ++k) {
            int e = eb + k;
            if (e < nE) {
                s[k] = es[e]; d[k] = ed[e];
                atomicAdd(&h[d[k] >> 8], 1);
            } else d[k] = -1;
        }
    }
    __syncthreads();
    {
        int t = threadIdx.x;
        int a = h[2 * t], b2 = h[2 * t + 1];
        sh[t] = a + b2;
        __syncthreads();
        for (int off = 1; off < 256; off <<= 1) {
            int x = (t >= off) ? sh[t - off] : 0;
            __syncthreads();
            sh[t] += x;
            __syncthreads();
        }
        int excl = sh[t] - (a + b2);
        lcur[2 * t] = excl;
        lcur[2 * t + 1] = excl + a;
    }
    __syncthreads();
    for (int b = threadIdx.x; b < NBMAX; b += 256) {
        int c = h[b];
        if (c) {
            int g = atomicAdd(&cur[b], c);
            h[b] = g - lcur[b];
        }
    }
    __syncthreads();
    if (eb + BIN_CH <= nE) {
#pragma unroll
        for (int k = 0; k < BIN_CH; ++k) {
            int b = d[k] >> 8;
            int pos = atomicAdd(&lcur[b], 1);
            stage[pos] = ((unsigned)(d[k] & 255) << 24) | (unsigned)s[k];
            stageB[pos] = (unsigned short)b;
        }
    } else {
#pragma unroll
        for (int k = 0; k < BIN_CH; ++k) {
            if (d[k] >= 0) {
                int b = d[k] >> 8;
                int pos = atomicAdd(&lcur[b], 1);
                stage[pos] = ((unsigned)(d[k] & 255) << 24) | (unsigned)s[k];
                stageB[pos] = (unsigned short)b;
            }
        }
    }
    __syncthreads();
    int total = nE - e0; if (total > BIN_EDGES) total = BIN_EDGES;
    for (int i = threadIdx.x; i < total; i += 256)
        pr[h[stageB[i]] + i] = stage[i];
}

// within-bucket fine sort; srcs writes staged in LDS -> full-line stores.
// 512 threads (2x waves/CU); 256-entry scan on first 256 lanes.
__global__ __launch_bounds__(512) void k_bucket_fine(
    const unsigned* __restrict__ pairs, const int* __restrict__ base,
    int* __restrict__ row0, int* __restrict__ srcs0,
    int* __restrict__ row1, int* __restrict__ srcs1,
    int n, int nE, int nb)
{
    const unsigned* pr = pairs + (size_t)blockIdx.y * nE;
    const int* ba = base + blockIdx.y * 528;
    int* row = blockIdx.y ? row1 : row0;
    int* srcs = blockIdx.y ? srcs1 : srcs0;
    __shared__ int cnt[256], cur[256];
    __shared__ int stage[FINE_CAP];
    int b = blockIdx.x;
    int t = threadIdx.x;
    int s0 = ba[b], s1 = ba[b + 1];
    int m = s1 - s0;
    if (t < 256) cnt[t] = 0;
    __syncthreads();
    for (int i = s0 + t; i < s1; i += 512)
        atomicAdd(&cnt[pr[i] >> 24], 1);
    __syncthreads();
    int c = (t < 256) ? cnt[t] : 0;
    if (t < 256) cur[t] = c;
    __syncthreads();
    for (int off = 1; off < 256; off <<= 1) {
        int x = (t < 256 && t >= off) ? cur[t - off] : 0;
        __syncthreads();
        if (t < 256) cur[t] += x;
        __syncthreads();
    }
    int excl = (t < 256) ? (cur[t] - c) : 0;
    __syncthreads();
    int node = (b << 8) + t;
    if (t < 256 && node < n) row[node] = s0 + excl;
    if (b == nb - 1 && t == 0) row[n] = nE;
    if (m <= FINE_CAP) {
        if (t < 256) cur[t] = excl;          // bucket-local cursor
        __syncthreads();
        for (int i = s0 + t; i < s1; i += 512) {
            unsigned p = pr[i];
            int slot = atomicAdd(&cur[p >> 24], 1);
            stage[slot] = (int)(p & 0xFFFFFFu);
        }
        __syncthreads();
        for (int i = t; i < m; i += 512)     // coalesced copy-out
            srcs[s0 + i] = stage[i];
    } else {                                 // fallback: direct scatter
        if (t < 256) cur[t] = s0 + excl;
        __syncthreads();
        for (int i = s0 + t; i < s1; i += 512) {
            unsigned p = pr[i];
            int slot = atomicAdd(&cur[p >> 24], 1);
            srcs[slot] = (int)(p & 0xFFFFFFu);
        }
    }
}

// ---------------- dense compute ----------------

struct TArgs2 {
    const void* __restrict__ x;
    const float* __restrict__ w;     // [128][32] packed self||nbr
    const float* __restrict__ b;     // [16]
    float* __restrict__ acc;
    void* __restrict__ nbr;
};

// 64-node / 32KB f32 LDS tile; bf16 converted once at staging.
// 512 threads = 8 waves, 4 cols/wave (jq wave-uniform); batched ds_reads.
// (R22 config: s_load weights — the empirical optimum of this family.)
__global__ __launch_bounds__(512) void k_transform1(
    TArgs2 a0, TArgs2 a1, int n, const int* __restrict__ flag)
{
    TArgs2 A = blockIdx.y ? a1 : a0;
    const int isf32 = *flag;
    __shared__ float xs[64 * 128];              // 32 KB
    const int t = threadIdx.x;
    const int tile0 = blockIdx.x * 64;

    if (isf32) {
        const float4* xg = (const float4*)A.x;  // 16B units
        float4* xl = (float4*)xs;
#pragma unroll
        for (int i = 0; i < 4; ++i) {           // 64 rows x 32 chunks
            int flat = i * 512 + t;
            int row = flat >> 5, ck = flat & 31;
            if (tile0 + row < n)
                xl[row * 32 + (ck ^ (row & 7))] =
                    xg[((size_t)(tile0 + row)) * 32 + ck];
        }
    } else {
        const uint4* xg = (const uint4*)A.x;
        float4* xl = (float4*)xs;
#pragma unroll
        for (int i = 0; i < 2; ++i) {           // 64 rows x 16 bf16-chunks
            int flat = i * 512 + t;
            int row = flat >> 4, ck = flat & 15;
            if (tile0 + row < n) {
                uint4 q = xg[((size_t)(tile0 + row)) * 16 + ck];
                float4 lo = make_float4(bflo(q.x), bfhi(q.x), bflo(q.y), bfhi(q.y));
                float4 hi = make_float4(bflo(q.z), bfhi(q.z), bflo(q.w), bfhi(q.w));
                xl[row * 32 + ((2 * ck) ^ (row & 7))] = lo;
                xl[row * 32 + ((2 * ck + 1) ^ (row & 7))] = hi;
            }
        }
    }
    __syncthreads();

    const int jq = __builtin_amdgcn_readfirstlane(t >> 6); // col octile 0..7
    const int r = t & 63;                                  // tile-local row
    const int node = tile0 + r;
    if (node >= n) return;
    const float* __restrict__ Wb = A.w + 4 * jq;
    const int sw = r & 7;

    float acc[4];
    if (jq < 4) {
#pragma unroll
        for (int j = 0; j < 4; ++j) acc[j] = A.b[4 * jq + j];
    } else {
#pragma unroll
        for (int j = 0; j < 4; ++j) acc[j] = 0.f;
    }

    const float4* xl = (const float4*)xs + r * 32;
    for (int kb = 0; kb < 4; ++kb) {            // 4 batches of 8 chunks
        float4 xq[8];
#pragma unroll
        for (int u = 0; u < 8; ++u)             // 8 ds_reads issued together
            xq[u] = xl[(kb * 8 + u) ^ sw];
#pragma unroll
        for (int u = 0; u < 8; ++u) {           // 128 FMAs; s_loads pipeline
            int kk = kb * 8 + u;
            float xv[4] = {xq[u].x, xq[u].y, xq[u].z, xq[u].w};
#pragma unroll
            for (int h = 0; h < 4; ++h) {
                const float* __restrict__ w0 = Wb + (kk * 4 + h) * 32;
#pragma unroll
                for (int j = 0; j < 4; ++j) acc[j] += xv[h] * w0[j];
            }
        }
    }

    if (jq < 4) {
        float4* a4 = (float4*)(A.acc + (size_t)node * 16);
        a4[jq] = make_float4(acc[0], acc[1], acc[2], acc[3]);
    } else {
        unsigned short* nrow = (unsigned short*)A.nbr + ((size_t)node << 4)
                               + ((jq - 4) << 2);
        *(uint2*)nrow = make_uint2(pack2bf(acc[0], acc[1]),
                                   pack2bf(acc[2], acc[3]));
    }
}

struct GArgs { const int *row, *srcs; const void* val; float* out; void* rout; };

// out[node,0:16] (f32) = (selfmode ? out[node] : 0) + sum_{nbrs} bf16row val[s]
// selfmode additionally writes rout[node] = bf16(relu(out-row)).
// 1D grid; graph = blockIdx&1 (XCD parity: one 3.2MB val table per XCD L2).
// 4 lanes/node = 2 col-halves x 2 edge-halves; shfl_xor(2) combine.
__global__ __launch_bounds__(256) void k_gather16(
    GArgs g0, GArgs g1, int n, int selfmode)
{
    GArgs G = (blockIdx.x & 1) ? g1 : g0;
    int t = (blockIdx.x >> 1) * 256 + threadIdx.x;
    int node = t >> 2;
    if (node >= n) return;
    const int q = t & 3;
    const int e2 = q >> 1;          // edge half
    const int c = (q & 1) << 3;     // bf16 col offset: 0 or 8
    const unsigned short* vb = (const unsigned short*)G.val;
    int rs = G.row[node], re = G.row[node + 1];
    int half = (re - rs + 1) >> 1;
    int jb = e2 ? (rs + half) : rs;
    int je = e2 ? re : (rs + half);
    float4 sa = make_float4(0.f, 0.f, 0.f, 0.f);
    float4 sb = make_float4(0.f, 0.f, 0.f, 0.f);
    int j = jb;
    for (; j + 16 <= je; j += 16) {
        int s[16];
        uint4 v[16];
#pragma unroll
        for (int u = 0; u < 16; ++u) s[u] = G.srcs[j + u];
#pragma unroll
        for (int u = 0; u < 16; ++u)
            v[u] = *(const uint4*)(vb + (((size_t)s[u]) << 4) + c);
#pragma unroll
        for (int u = 0; u < 16; ++u) {
            sa.x += bflo(v[u].x); sa.y += bfhi(v[u].x);
            sa.z += bflo(v[u].y); sa.w += bfhi(v[u].y);
            sb.x += bflo(v[u].z); sb.y += bfhi(v[u].z);
            sb.z += bflo(v[u].w); sb.w += bfhi(v[u].w);
        }
    }
    for (; j + 8 <= je; j += 8) {
        int s[8];
        uint4 v[8];
#pragma unroll
        for (int u = 0; u < 8; ++u) s[u] = G.srcs[j + u];
#pragma unroll
        for (int u = 0; u < 8; ++u)
            v[u] = *(const uint4*)(vb + (((size_t)s[u]) << 4) + c);
#pragma unroll
        for (int u = 0; u < 8; ++u) {
            sa.x += bflo(v[u].x); sa.y += bfhi(v[u].x);
            sa.z += bflo(v[u].y); sa.w += bfhi(v[u].y);
            sb.x += bflo(v[u].z); sb.y += bfhi(v[u].z);
            sb.z += bflo(v[u].w); sb.w += bfhi(v[u].w);
        }
    }
    for (; j < je; ++j) {
        uint4 v = *(const uint4*)(vb + (((size_t)G.srcs[j]) << 4) + c);
        sa.x += bflo(v.x); sa.y += bfhi(v.x);
        sa.z += bflo(v.y); sa.w += bfhi(v.y);
        sb.x += bflo(v.z); sb.y += bfhi(v.z);
        sb.z += bflo(v.w); sb.w += bfhi(v.w);
    }
    // combine edge halves (lanes differ in bit 1)
    sa.x += __shfl_xor(sa.x, 2); sa.y += __shfl_xor(sa.y, 2);
    sa.z += __shfl_xor(sa.z, 2); sa.w += __shfl_xor(sa.w, 2);
    sb.x += __shfl_xor(sb.x, 2); sb.y += __shfl_xor(sb.y, 2);
    sb.z += __shfl_xor(sb.z, 2); sb.w += __shfl_xor(sb.w, 2);
    if (e2 == 0) {
        float4* o4 = (float4*)(G.out + ((size_t)node << 4) + c);
        if (selfmode) {
            float4 pa = o4[0], pb = o4[1];
            sa.x += pa.x; sa.y += pa.y; sa.z += pa.z; sa.w += pa.w;
            sb.x += pb.x; sb.y += pb.y; sb.z += pb.z; sb.w += pb.w;
        }
        o4[0] = sa; o4[1] = sb;
        if (selfmode) {
            unsigned short* orow = (unsigned short*)G.rout + ((size_t)node << 4) + c;
            *(uint4*)orow = make_uint4(
                pack2bf(fmaxf(sa.x, 0.f), fmaxf(sa.y, 0.f)),
                pack2bf(fmaxf(sa.z, 0.f), fmaxf(sa.w, 0.f)),
                pack2bf(fmaxf(sb.x, 0.f), fmaxf(sb.y, 0.f)),
                pack2bf(fmaxf(sb.z, 0.f), fmaxf(sb.w, 0.f)));
        }
    }
}

// fp[30] accumulate: fp += f(row) @ C[:, jo:jo+30]  where C is [16][60] at wb+off
__device__ __forceinline__ void fp_acc30(float* fp, const float* __restrict__ wb,
                                         int off, int jo,
                                         const float* __restrict__ row, bool dorelu)
{
    const float4* r4 = (const float4*)row;
    for (int kk = 0; kk < 4; ++kk) {
        float4 v = r4[kk];
        float xs[4] = {v.x, v.y, v.z, v.w};
        if (dorelu) {
            xs[0] = fmaxf(xs[0], 0.f); xs[1] = fmaxf(xs[1], 0.f);
            xs[2] = fmaxf(xs[2], 0.f); xs[3] = fmaxf(xs[3], 0.f);
        }
        const float* __restrict__ wq = wb + off + kk * 240 + jo;
#pragma unroll
        for (int h = 0; h < 4; ++h) {
#pragma unroll
            for (int j = 0; j < 30; ++j) fp[j] += xs[h] * wq[h * 60 + j];
        }
    }
}

// fused layer2(nbr part via folded weights) + MLP head; 128 nodes/block,
// wave pairs split fp[60] -> fp[30] each; h[10] partials combined via LDS.
__global__ __launch_bounds__(256) void k_headf(
    const float* __restrict__ hP, const float* __restrict__ gP,
    const float* __restrict__ hL, const float* __restrict__ gL,
    const void* __restrict__ action, const float* __restrict__ wb,
    void* __restrict__ out, int n, const int* __restrict__ flag)
{
    const int isf32 = *flag;
    __shared__ float hbuf[128][10];
    int w = threadIdx.x >> 6;
    int jh = __builtin_amdgcn_readfirstlane(w & 1);
    int slot = ((w >> 1) << 6) + (threadIdx.x & 63);
    int node = blockIdx.x * 128 + slot;
    int nodec = node < n ? node : (n - 1);
    const int jo = 30 * jh;

    float fp[30];
#pragma unroll
    for (int j = 0; j < 30; ++j) fp[j] = wb[OBIN + jo + j];

    fp_acc30(fp, wb, OC1P, jo, hP + (size_t)nodec * 16, true);
    fp_acc30(fp, wb, OC2P, jo, gP + (size_t)nodec * 16, false);
    fp_acc30(fp, wb, OC1L, jo, hL + (size_t)nodec * 16, true);
    fp_acc30(fp, wb, OC2L, jo, gL + (size_t)nodec * 16, false);

    float h[10];
#pragma unroll
    for (int j = 0; j < 10; ++j) h[j] = (jh == 0) ? wb[OBHID + j] : 0.f;
#pragma unroll
    for (int k = 0; k < 30; ++k) {
        float v = fmaxf(fp[k], 0.f);
#pragma unroll
        for (int j = 0; j < 10; ++j) h[j] += v * wb[OWHID + (jo + k) * 10 + j];
    }
    if (jh) {
#pragma unroll
        for (int j = 0; j < 10; ++j) hbuf[slot][j] = h[j];
    }
    __syncthreads();
    if (jh == 0) {
#pragma unroll
        for (int j = 0; j < 10; ++j) h[j] += hbuf[slot][j];
#pragma unroll
        for (int k = 0; k < 10; ++k) {
            float v = ldf(action, isf32, (size_t)nodec * 10 + k);
#pragma unroll
            for (int j = 0; j < 10; ++j) h[j] += v * wb[OWHID + (60 + k) * 10 + j];
        }
        float o = wb[OBOUT];
#pragma unroll
        for (int j = 0; j < 10; ++j) o += fmaxf(h[j], 0.f) * wb[OWOUT + j];
        if (node < n) {
            if (isf32) ((float*)out)[node] = o;
            else       ((unsigned short*)out)[node] = f2bf(o);
        }
    }
}

extern "C" void kernel_launch(void* const* d_in, const int* in_sizes, int n_in,
                              void* d_out, int out_size, void* d_ws, size_t ws_size,
                              hipStream_t stream)
{
    const void* px   = d_in[0];
    const int*  pe   = (const int*)d_in[1];
    const void* lx   = d_in[2];
    const int*  le   = (const int*)d_in[3];
    const void* act  = d_in[4];

    const int N = in_sizes[0] / F_IN;
    const int E = in_sizes[1] / 2;
    const int NB = (N + 255) >> 8;

    // header: flag(64) | cnt(2*512) | base(2*528) | cursor(2*512) = 3200 ints
    int* flag    = (int*)d_ws;
    int* cnt     = flag + 64;
    int* base    = cnt + 2 * NBMAX;
    int* cursorB = base + 2 * 528;
    float* wbuf  = (float*)(flag + 3200);
    int* rowP    = flag + 3200 + WBUF_FLOATS;
    int* srcsP   = rowP + (N + 64);
    int* rowL    = srcsP + E;
    int* srcsL   = rowL + (N + 64);
    float* dense = (float*)(srcsL + E);
    unsigned* pairs = (unsigned*)dense;   // 2E uints; dead before dense writes

    float* accP = dense;                       // [N][16] f32 (h1_P, stays live)
    float* accL = accP + (size_t)N * 16;       // [N][16] f32
    float* aggP = accL + (size_t)N * 16;       // [N][16] f32 (gather-2 out)
    float* aggL = aggP + (size_t)N * 16;       // [N][16] f32
    void*  n1P  = (void*)(aggL + (size_t)N * 16);       // [N][16] bf16
    void*  n1L  = (void*)((float*)n1P + (size_t)N * 8); // [N][16] bf16
    void*  n2P  = (void*)((float*)n1L + (size_t)N * 8); // [N][16] bf16 relu(h1)
    void*  n2L  = (void*)((float*)n2P + (size_t)N * 8); // [N][16] bf16

    const int nb64 = (N + 63) / 64;
    const int nb128 = (N + 127) / 128;
    const int gb4 = (N * 4 + 255) / 256;
    const int bb = (E + BIN_EDGES - 1) / BIN_EDGES;

    // prepw: weights + per-block dtype probe + cnt zeroing
    PW P{d_in[5], d_in[6], d_in[7], d_in[11], d_in[12], d_in[13],
         d_in[8], d_in[9], d_in[10], d_in[14], d_in[15], d_in[16],
         d_in[17], d_in[18], d_in[19], d_in[20], d_in[21], d_in[22]};
    k_prepw<<<64, 256, 0, stream>>>(P, (const unsigned short*)px, wbuf,
                                    flag, cnt, 2 * NBMAX);

    // ---- CSR build for both graphs (blockIdx.y = graph) ----
    k_bucket_hist<<<dim3(256, 2), 256, 0, stream>>>(pe + E, le + E, cnt, E);
    k_bucket_scan<<<2, 512, 0, stream>>>(cnt, base, cursorB, NB);
    k_bucket_bin<<<dim3(bb, 2), 256, 0, stream>>>(pe, pe + E, le, le + E,
                                                  cursorB, pairs, E);
    k_bucket_fine<<<dim3(NB, 2), 512, 0, stream>>>(pairs, base, rowP, srcsP,
                                                   rowL, srcsL, N, E, NB);

    // ---- dense pipeline ----
    TArgs2 tP{px, wbuf + OW1P, wbuf + OB1P, accP, n1P};
    TArgs2 tL{lx, wbuf + OW1L, wbuf + OB1L, accL, n1L};
    k_transform1<<<dim3(nb64, 2), 512, 0, stream>>>(tP, tL, N, flag);

    // gather-1 (self+agg), fused relu->bf16 into n2; 1D grid, graph=bid&1
    GArgs g1P{rowP, srcsP, n1P, accP, n2P}, g1L{rowL, srcsL, n1L, accL, n2L};
    k_gather16<<<gb4 * 2, 256, 0, stream>>>(g1P, g1L, N, 1);

    // gather-2 (agg of relu'd h1)
    GArgs g2P{rowP, srcsP, n2P, aggP, nullptr}, g2L{rowL, srcsL, n2L, aggL, nullptr};
    k_gather16<<<gb4 * 2, 256, 0, stream>>>(g2P, g2L, N, 0);

    k_headf<<<nb128, 256, 0, stream>>>(accP, aggP, accL, aggL, act, wbuf,
                                       d_out, N, flag);
}